// Round 1
// baseline (137.557 us; speedup 1.0000x reference)
//
#include <hip/hip_runtime.h>
#include <cstddef>

#define BB 16
#define PP 4
#define HH 32
#define WW 32
#define DD 32
#define CC 8

// One thread per (b,p,h,w,d) voxel; handles all 8 channels via float4 pairs.
// 128 blocks of 256 threads per (b,p) slice -> theta is wave-uniform (scalar loads).
__global__ __launch_bounds__(256) void resample_kernel(
    const float* __restrict__ fmap,
    const float* __restrict__ theta,
    float* __restrict__ out)
{
    const int bp  = blockIdx.x >> 7;                       // 32768 voxels / 256 = 128 chunks per (b,p)
    const int vox = ((blockIdx.x & 127) << 8) | threadIdx.x;
    const int d = vox & 31;
    const int w = (vox >> 5) & 31;
    const int h = vox >> 10;

    const float* th = theta + bp * 12;
    const float fw = (float)w, fh = (float)h, fd = (float)d;
    // x uses theta row 0 with (w,h,d,1) per meshgrid 'xy' semantics; +2 pad offset
    const float x = fmaf(th[0], fw, fmaf(th[1], fh, fmaf(th[2],  fd, th[3] ))) + 2.0f;
    const float y = fmaf(th[4], fw, fmaf(th[5], fh, fmaf(th[6],  fd, th[7] ))) + 2.0f;
    const float z = fmaf(th[8], fw, fmaf(th[9], fh, fmaf(th[10], fd, th[11]))) + 2.0f;

    // faithful: floor -> int -> clip to [0, H+2] in padded coords (all axes use H+2)
    int x0 = min(max((int)floorf(x), 0), HH + 2);
    int y0 = min(max((int)floorf(y), 0), HH + 2);
    int z0 = min(max((int)floorf(z), 0), HH + 2);
    const float xd = x - (float)x0, yd = y - (float)y0, zd = z - (float)z0;
    const float xm = 1.0f - xd,     ym = 1.0f - yd,     zm = 1.0f - zd;

    // unpadded indices (pad was 2); out-of-range corner == read of zero-pad -> contribute 0
    const int ix0 = x0 - 2, iy0 = y0 - 2, iz0 = z0 - 2;
    const float* __restrict__ base = fmap + (size_t)bp * (HH * WW * DD * CC);

    float4 aA = make_float4(0.f, 0.f, 0.f, 0.f);
    float4 aB = make_float4(0.f, 0.f, 0.f, 0.f);

    #pragma unroll
    for (int cx = 0; cx < 2; ++cx) {
        const int ix = ix0 + cx;
        const bool vx = (unsigned)ix < (unsigned)HH;     // x indexes the H axis (reference quirk)
        const float wx = cx ? xd : xm;
        #pragma unroll
        for (int cy = 0; cy < 2; ++cy) {
            const int iy = iy0 + cy;
            const bool vxy = vx && ((unsigned)iy < (unsigned)WW);
            const float wxy = wx * (cy ? yd : ym);
            #pragma unroll
            for (int cz = 0; cz < 2; ++cz) {
                const int iz = iz0 + cz;
                const float wgt = wxy * (cz ? zd : zm);
                if (vxy && ((unsigned)iz < (unsigned)DD)) {
                    const float4* p = (const float4*)(base + (size_t)(((ix * WW + iy) * DD + iz) * CC));
                    const float4 a = p[0];
                    const float4 b = p[1];
                    aA.x = fmaf(wgt, a.x, aA.x);
                    aA.y = fmaf(wgt, a.y, aA.y);
                    aA.z = fmaf(wgt, a.z, aA.z);
                    aA.w = fmaf(wgt, a.w, aA.w);
                    aB.x = fmaf(wgt, b.x, aB.x);
                    aB.y = fmaf(wgt, b.y, aB.y);
                    aB.z = fmaf(wgt, b.z, aB.z);
                    aB.w = fmaf(wgt, b.w, aB.w);
                }
            }
        }
    }

    float4* o = (float4*)(out + (size_t)(bp * (HH * WW * DD) + vox) * CC);
    o[0] = aA;
    o[1] = aB;
}

extern "C" void kernel_launch(void* const* d_in, const int* in_sizes, int n_in,
                              void* d_out, int out_size, void* d_ws, size_t ws_size,
                              hipStream_t stream) {
    const float* fmap  = (const float*)d_in[0];
    const float* theta = (const float*)d_in[1];
    float* out = (float*)d_out;

    const int total_blocks = BB * PP * ((HH * WW * DD) / 256);  // 64 * 128 = 8192
    resample_kernel<<<dim3(total_blocks), dim3(256), 0, stream>>>(fmap, theta, out);
}

// Round 3
// 122.425 us; speedup vs baseline: 1.1236x; 1.1236x over previous
//
#include <hip/hip_runtime.h>
#include <cstddef>

#define BB 16
#define PP 4
#define HH 32
#define WW 32
#define DD 32
#define CC 8

typedef float fx4 __attribute__((ext_vector_type(4)));

// Two threads per voxel (one per 4-channel half). Branch-free: corner loads are
// unconditional with clamped addresses; out-of-volume corners get weight 0.
// All 8 float4 loads issued before the FMA chain -> full memory-level parallelism.
__global__ __launch_bounds__(256) void resample_kernel(
    const float* __restrict__ fmap,
    const float* __restrict__ theta,
    float* __restrict__ out)
{
    // 256 blocks per (b,p): 32768 voxels * 2 threads / 256
    const int bp   = blockIdx.x >> 8;
    const int tid  = threadIdx.x;
    const int vox  = ((blockIdx.x & 255) << 7) | (tid >> 1);   // voxel index in [0, 32768)
    const int half = tid & 1;                                   // which float4 of the 8 channels
    const int d = vox & 31;
    const int w = (vox >> 5) & 31;
    const int h = vox >> 10;

    const float* th = theta + bp * 12;
    const float fw = (float)w, fh = (float)h, fd = (float)d;
    // meshgrid 'xy': at (h,w,d) the grid point is (x=w, y=h, z=d); +2 for pad offset
    const float x = fmaf(th[0], fw, fmaf(th[1], fh, fmaf(th[2],  fd, th[3] ))) + 2.0f;
    const float y = fmaf(th[4], fw, fmaf(th[5], fh, fmaf(th[6],  fd, th[7] ))) + 2.0f;
    const float z = fmaf(th[8], fw, fmaf(th[9], fh, fmaf(th[10], fd, th[11]))) + 2.0f;

    // faithful: floor -> clip to [0, H+2] in padded coords (all axes use H+2)
    const int x0 = min(max((int)floorf(x), 0), HH + 2);
    const int y0 = min(max((int)floorf(y), 0), HH + 2);
    const int z0 = min(max((int)floorf(z), 0), HH + 2);
    const float xd = x - (float)x0, yd = y - (float)y0, zd = z - (float)z0;

    // unpadded corner indices (pad=2); validity per axis per corner
    const int ix[2] = { x0 - 2, x0 - 1 };
    const int iy[2] = { y0 - 2, y0 - 1 };
    const int iz[2] = { z0 - 2, z0 - 1 };
    const float wxv[2] = { (1.0f - xd) * (((unsigned)ix[0] < (unsigned)HH) ? 1.0f : 0.0f),
                           xd          * (((unsigned)ix[1] < (unsigned)HH) ? 1.0f : 0.0f) };
    const float wyv[2] = { (1.0f - yd) * (((unsigned)iy[0] < (unsigned)WW) ? 1.0f : 0.0f),
                           yd          * (((unsigned)iy[1] < (unsigned)WW) ? 1.0f : 0.0f) };
    const float wzv[2] = { (1.0f - zd) * (((unsigned)iz[0] < (unsigned)DD) ? 1.0f : 0.0f),
                           zd          * (((unsigned)iz[1] < (unsigned)DD) ? 1.0f : 0.0f) };
    // clamped (always in-range) indices for the unconditional loads
    const int cx[2] = { min(max(ix[0], 0), HH - 1), min(max(ix[1], 0), HH - 1) };
    const int cy[2] = { min(max(iy[0], 0), WW - 1), min(max(iy[1], 0), WW - 1) };
    const int cz[2] = { min(max(iz[0], 0), DD - 1), min(max(iz[1], 0), DD - 1) };

    const float* __restrict__ base = fmap + (size_t)bp * (HH * WW * DD * CC) + half * 4;

    // Issue all 8 loads first (no branches -> back-to-back global_load_dwordx4)
    fx4   c[8];
    float wgt[8];
    #pragma unroll
    for (int i = 0; i < 8; ++i) {
        const int bx = (i >> 2) & 1, by = (i >> 1) & 1, bz = i & 1;
        const size_t off = (size_t)(((cx[bx] * WW + cy[by]) * DD + cz[bz]) * CC);
        c[i]   = *(const fx4*)(base + off);
        wgt[i] = wxv[bx] * wyv[by] * wzv[bz];
    }

    fx4 acc = (fx4){0.f, 0.f, 0.f, 0.f};
    #pragma unroll
    for (int i = 0; i < 8; ++i) {
        acc.x = fmaf(wgt[i], c[i].x, acc.x);
        acc.y = fmaf(wgt[i], c[i].y, acc.y);
        acc.z = fmaf(wgt[i], c[i].z, acc.z);
        acc.w = fmaf(wgt[i], c[i].w, acc.w);
    }

    fx4* o = (fx4*)(out + (size_t)(bp * (HH * WW * DD) + vox) * CC + half * 4);
    __builtin_nontemporal_store(acc, o);
}

extern "C" void kernel_launch(void* const* d_in, const int* in_sizes, int n_in,
                              void* d_out, int out_size, void* d_ws, size_t ws_size,
                              hipStream_t stream) {
    const float* fmap  = (const float*)d_in[0];
    const float* theta = (const float*)d_in[1];
    float* out = (float*)d_out;

    const int total_blocks = BB * PP * 256;   // 16384 blocks of 256 threads (2 thr/voxel)
    resample_kernel<<<dim3(total_blocks), dim3(256), 0, stream>>>(fmap, theta, out);
}